// Round 7
// baseline (161.902 us; speedup 1.0000x reference)
//
#include <hip/hip_runtime.h>

// DownSample (fp32 in/out, bf16 MFMA internals), MI355X gfx950
// Shapes: B=128, n_stk=32, n_stk_pnt=32, COOR=32, m=16, k=2
// outputs: sparse_out [128,256,16] | dense_out [128,128,16,16] | coor_out [128,16,32]
//
// R15: latency round. R14's rolled loops serialize a ~250cy L2 weight wait
// per MFMA-loop iteration (8+12+16 iters = the critical path). Fix within the
// <=64-VGPR/8-block regime: 2-deep rotating weight prefetch in every MFMA
// loop (consume slot kt, issue load kt+2; tail prefetch reads harmlessly into
// the adjacent ws region -> branchless rolled body), slot init hoisted above
// the preceding barrier. v_cvt_pk_bf16_f32 replaces hand-rolled f2bf for the
// dense stage pack (+epi1 pairs): ~170 fewer VALU instr/thread.
// launch_bounds(256,8) pins the 64-VGPR budget (est. peak ~56: no spill).

typedef unsigned short u16;
typedef unsigned int   u32;
typedef __attribute__((ext_vector_type(8))) short bf16x8;   // 4 VGPRs
typedef __attribute__((ext_vector_type(4))) float f32x4;

#define BN_SCALE 0.9999950000374997f   // 1/sqrt(1+1e-5)

__device__ __forceinline__ float gelu_f(float x){
  return 0.5f*x*(1.0f + erff(x*0.70710678118654752f));
}
__device__ __forceinline__ u16 f2bf(float f){
  u32 x = __float_as_uint(f);
  x += 0x7fffu + ((x>>16)&1u);           // RNE
  return (u16)(x>>16);
}
// packed RNE f32x2 -> bf16x2 (low=a, high=b); gfx950 HW instr
__device__ __forceinline__ u32 cvtpk(float a, float b){
  u32 d;
  asm("v_cvt_pk_bf16_f32 %0, %1, %2" : "=v"(d) : "v"(a), "v"(b));
  return d;
}
#define MFMA16(a,b,c) __builtin_amdgcn_mfma_f32_16x16x32_bf16(a,b,c,0,0,0)

// ---------------- kernel 1: weight swizzle (blocks 0..831) + FPS (832..959) ----------------
// A-frag layout: afrag[(kt*NT + ot)*64 + lane][j] = W[o = ot*16+(lane&15)][k = kt*32+((lane>>4)&3)*8+j]
__global__ __launch_bounds__(256) void k_prep(
    const float* __restrict__ dn_w, const float* __restrict__ ds_w, const float* __restrict__ sp_w,
    const float* __restrict__ coor,
    u16* __restrict__ wdb, u16* __restrict__ wcb, u16* __restrict__ wsb,
    int* __restrict__ fps_idx, int* __restrict__ nn_idx, float* __restrict__ coor_out)
{
  int blk = blockIdx.x, t = threadIdx.x;
  if (blk < 128){                       // dense MLP W [128o x 256k] -> 8kt x 8ot
    int w = blk*256 + t;
    int j=w&7, lane=(w>>3)&63, tile=w>>9;
    int kt=tile>>3, ot=tile&7;
    int o=ot*16+(lane&15), i=kt*32+((lane>>4)&3)*8+j;
    wdb[w] = f2bf(dn_w[o*256+i]);
  } else if (blk < 320){                // conv W [128o x 384k] -> 12kt x 8ot
    int w = (blk-128)*256 + t;
    int j=w&7, lane=(w>>3)&63, tile=w>>9;
    int kt=tile>>3, ot=tile&7;
    int o=ot*16+(lane&15), k=kt*32+((lane>>4)&3)*8+j;
    wcb[w] = f2bf(ds_w[o*384+k]);
  } else if (blk < 832){                // sparse W [256o x 512k] -> 16kt x 16ot
    int w = (blk-320)*256 + t;
    int j=w&7, lane=(w>>3)&63, tile=w>>9;
    int kt=tile>>4, ot=tile&15;
    int o=ot*16+(lane&15), i=kt*32+((lane>>4)&3)*8+j;
    wsb[w] = f2bf(sp_w[o*512+i]);
  } else {
    // ---- FPS + NN + coor_out for b = blk-832 ----
    int b = blk - 832;
    __shared__ float Xs[32*33];
    __shared__ float D[32*33];
    __shared__ int   s_sel[16];
    for (int i=t;i<1024;i+=256) Xs[(i>>5)*33 + (i&31)] = coor[b*1024+i];
    __syncthreads();
    #pragma unroll
    for (int k2=0;k2<4;k2++){
      int p=t+k2*256, i=p>>5, j=p&31;
      float d=0.f;
      #pragma unroll
      for (int c=0;c<32;c++){ float df=Xs[i*33+c]-Xs[j*33+c]; d+=df*df; }
      D[i*33+j]=d;
    }
    __syncthreads();
    if (t < 64){
      int j = t & 31;
      float dist = 3.0e38f;
      int far = 0;
      #pragma unroll
      for (int it=0; it<16; ++it){
        if (t==0) s_sel[it]=far;
        dist = fminf(dist, D[far*33+j]);
        float v=dist; int idx=j;              // argmax, first-index tie-break
        #pragma unroll
        for (int off=16; off>=1; off>>=1){
          float v2=__shfl_xor(v,off,32); int i2=__shfl_xor(idx,off,32);
          if (v2>v || (v2==v && i2<idx)){ v=v2; idx=i2; }
        }
        far = idx;
      }
      if (t==0){
        #pragma unroll
        for (int it=0;it<16;++it) fps_idx[b*16+it]=s_sel[it];
      }
    }
    __syncthreads();
    {
      int wv=t>>6, j=t&31;
      #pragma unroll
      for (int q=0;q<4;q++){
        int it = wv*4+q, sel = s_sel[it];
        float d = D[sel*33+j];
        if (j==sel) d=3.0e38f;
        float v=d; int idx=j;                 // argmin, first-index tie-break
        #pragma unroll
        for (int off=16; off>=1; off>>=1){
          float v2=__shfl_xor(v,off,32); int i2=__shfl_xor(idx,off,32);
          if (v2<v || (v2==v && i2<idx)){ v=v2; idx=i2; }
        }
        if ((t&63)==0) nn_idx[b*16+it]=idx;
      }
    }
    for (int q=t;q<512;q+=256){
      int mm=q>>5, c=q&31;
      coor_out[b*512+q] = Xs[s_sel[mm]*33 + c];
    }
  }
}

// ---------------- kernel 2: fused sparse (blocks 0..127, 1 b each) + dense (128..2175, 1 m each) ----
__global__ __launch_bounds__(256,8) void k_main(
    const float* __restrict__ sfea, const u16* __restrict__ wsb,
    const float* __restrict__ sp_b, const float* __restrict__ sp_g, const float* __restrict__ sp_be,
    const float* __restrict__ dfea, const u16* __restrict__ wdb,
    const float* __restrict__ dn_b, const float* __restrict__ dn_g, const float* __restrict__ dn_be,
    const u16* __restrict__ wcb,
    const float* __restrict__ ds_b, const float* __restrict__ ds_g, const float* __restrict__ ds_be,
    const int* __restrict__ fps_idx, const int* __restrict__ nn_idx,
    float* __restrict__ out_sp, float* __restrict__ out_dn)
{
  __shared__ char smem[19456];
  __shared__ int SI[32];
  int blk=blockIdx.x;
  int t=threadIdx.x, lane=t&63, wv=t>>6, quad=lane>>4, col=lane&15;
  if (blk < 128){
    // ======== sparse: b = blk; C = W[256o x 512i] * X[512i x 16m] ========
    int b = blk;
    u16*   Xb = (u16*)smem;                      // [16m][520] u16 = 16640 B
    float* P  = (float*)(smem+16640);            // spA | spB : 512 f32 = 2048 B
    if (t<32){
      SI[t] = ((t<16) ? fps_idx[b*16+t] : nn_idx[b*16+(t-16)]) & 31;
    }
    { float A = sp_g[t]*BN_SCALE; P[t]=A; P[256+t]=fmaf(sp_b[t],A,sp_be[t]); }
    __syncthreads();
    {
      const float* row = sfea + b*8192 + t*32;   // channel t
      #pragma unroll 1
      for (int m=0;m<16;m++){
        float vc=row[SI[m]], vn=row[SI[16+m]];
        Xb[m*520 + t]       = f2bf(vn-vc);   // i<256: diff
        Xb[m*520 + 256 + t] = f2bf(vc);      // i>=256: ctr
      }
    }
    __syncthreads();
    #pragma unroll 1
    for (int oh=0;oh<2;oh++){
      f32x4 accA[2]={}, accB[2]={};              // [r]
      const u16* wB0 = wsb + ((oh*8+wv  )*64+lane)*8;   // kt stride = 8192 u16
      const u16* wB1 = wsb + ((oh*8+wv+4)*64+lane)*8;
      bf16x8 pa0 = *(const bf16x8*)(wB0);
      bf16x8 pa1 = *(const bf16x8*)(wB1);
      bf16x8 qa0 = *(const bf16x8*)(wB0 + 8192);
      bf16x8 qa1 = *(const bf16x8*)(wB1 + 8192);
      #pragma unroll 1
      for (int kt=0;kt<8;kt+=2){
        bf16x8 bf0 = *(const bf16x8*)&Xb[col*520 + kt*32 + quad*8];
        bf16x8 c0=pa0, c1=pa1;
        pa0 = *(const bf16x8*)(wB0 + (kt+2)*8192);
        pa1 = *(const bf16x8*)(wB1 + (kt+2)*8192);
        accA[0]=MFMA16(c0,bf0,accA[0]); accA[1]=MFMA16(c1,bf0,accA[1]);
        bf0 = *(const bf16x8*)&Xb[col*520 + (kt+1)*32 + quad*8];
        c0=qa0; c1=qa1;
        qa0 = *(const bf16x8*)(wB0 + (kt+3)*8192);
        qa1 = *(const bf16x8*)(wB1 + (kt+3)*8192);
        accA[0]=MFMA16(c0,bf0,accA[0]); accA[1]=MFMA16(c1,bf0,accA[1]);
      }
      // pa/qa now hold kt=8,9 -> seamless into the B half
      #pragma unroll 1
      for (int kt=8;kt<16;kt+=2){
        bf16x8 bf0 = *(const bf16x8*)&Xb[col*520 + kt*32 + quad*8];
        bf16x8 c0=pa0, c1=pa1;
        pa0 = *(const bf16x8*)(wB0 + (kt+2)*8192);   // tail reads past wsb: valid ws mem, dead regs
        pa1 = *(const bf16x8*)(wB1 + (kt+2)*8192);
        accB[0]=MFMA16(c0,bf0,accB[0]); accB[1]=MFMA16(c1,bf0,accB[1]);
        bf0 = *(const bf16x8*)&Xb[col*520 + (kt+1)*32 + quad*8];
        c0=qa0; c1=qa1;
        qa0 = *(const bf16x8*)(wB0 + (kt+3)*8192);
        qa1 = *(const bf16x8*)(wB1 + (kt+3)*8192);
        accB[0]=MFMA16(c0,bf0,accB[0]); accB[1]=MFMA16(c1,bf0,accB[1]);
      }
      #pragma unroll
      for (int r=0;r<2;r++){
        #pragma unroll
        for (int reg=0;reg<4;reg++){
          int o = oh*128 + (wv+r*4)*16 + quad*4 + reg;
          float A=P[o], Bv=P[256+o];
          float k1 = accA[r][reg]+accB[r][reg];  // k=1: [diff|ctr]
          float k0 = accB[r][reg];               // k=0: diff part exactly 0
          float v = fmaxf(gelu_f(fmaf(k1,A,Bv)), gelu_f(fmaf(k0,A,Bv)));
          out_sp[(b*256+o)*16 + col] = v;
        }
      }
    }
  } else {
    // ======== dense: d=blk-128; b=((d>>7)<<3)|(d&7); m=(d>>3)&15 ========
    int d=blk-128;
    int b = ((d>>7)<<3) | (d&7), m = (d>>3)&15;
    u16* Vb = (u16*)smem;                 // phase 1: [32p][264] bf16 = 16896 B
    u16* Bc = (u16*)smem;                 // phase 2: [16x][392] bf16 = 12544 B
    float* Pd = (float*)(smem+16896);     // dnA|dnB|dsA|dsB|a0 : 640 f32 = 2560 B
    int ci=fps_idx[b*16+m]&31, ni=nn_idx[b*16+m]&31;
    if (t < 128){                         // fold BN: out = gelu(acc*A + B)
      float A  = dn_g[t]*BN_SCALE; float Bv = fmaf(dn_b[t], A, dn_be[t]);
      float Ac = ds_g[t]*BN_SCALE; float Cv = fmaf(ds_b[t], Ac, ds_be[t]);
      Pd[t]=A; Pd[128+t]=Bv; Pd[256+t]=Ac; Pd[384+t]=Cv;
      Pd[512+t]=gelu_f(Bv);               // a0 (k=0 diff value)
    }
    const float* Db = dfea + b*131072;    // dfea[b][c][s][x]: c*1024 + s*32 + x
    #pragma unroll 1
    for (int it=0; it<2; it++){
      int w = t + it*256;                 // 0..511 : cpair(64) x xq(8)
      int c = (w>>3)*2, x = (w&7)*4;
      const float* base = Db + c*1024 + x;
      float4 fcA = *(const float4*)(base + ci*32);
      float4 fnA = *(const float4*)(base + ni*32);
      float4 fcB = *(const float4*)(base + 1024 + ci*32);
      float4 fnB = *(const float4*)(base + 1024 + ni*32);
      #pragma unroll
      for (int e=0;e<4;e++){
        int xx=x+e, dp=xx&1, p=xx>>1;
        float dA = ((const float*)&fnA)[e] - ((const float*)&fcA)[e];
        float dB = ((const float*)&fnB)[e] - ((const float*)&fcB)[e];
        *(u32*)&Vb[p*264 + dp*128 + c]      = cvtpk(dA, dB);                             // diff cols p<16
        *(u32*)&Vb[(16+p)*264 + dp*128 + c] = cvtpk(((const float*)&fcA)[e], ((const float*)&fcB)[e]); // ctr
      }
    }
    // MLP weight slots kt=0,1 prefetched above the barrier (L2 latency hides in drain)
    const u16* wdB0 = wdb + ((wv  )*64+lane)*8;       // kt stride = 4096 u16
    const u16* wdB1 = wdb + ((wv+4)*64+lane)*8;
    bf16x8 pa0 = *(const bf16x8*)(wdB0);
    bf16x8 pa1 = *(const bf16x8*)(wdB1);
    bf16x8 qa0 = *(const bf16x8*)(wdB0 + 4096);
    bf16x8 qa1 = *(const bf16x8*)(wdB1 + 4096);
    __syncthreads();
    // ---- dense MLP: C[128o x 32p]; acc[r][pt]; 2-deep weight pipe ----
    f32x4 acc[2][2]={};
    #pragma unroll 1
    for (int kt=0;kt<8;kt+=2){
      bf16x8 b0 = *(const bf16x8*)&Vb[col*264      + kt*32 + quad*8];
      bf16x8 b1 = *(const bf16x8*)&Vb[(16+col)*264 + kt*32 + quad*8];
      bf16x8 c0=pa0, c1=pa1;
      pa0 = *(const bf16x8*)(wdB0 + (kt+2)*4096);     // tail reads into wcb: valid, dead regs
      pa1 = *(const bf16x8*)(wdB1 + (kt+2)*4096);
      acc[0][0]=MFMA16(c0,b0,acc[0][0]); acc[0][1]=MFMA16(c0,b1,acc[0][1]);
      acc[1][0]=MFMA16(c1,b0,acc[1][0]); acc[1][1]=MFMA16(c1,b1,acc[1][1]);
      b0 = *(const bf16x8*)&Vb[col*264      + (kt+1)*32 + quad*8];
      b1 = *(const bf16x8*)&Vb[(16+col)*264 + (kt+1)*32 + quad*8];
      c0=qa0; c1=qa1;
      qa0 = *(const bf16x8*)(wdB0 + (kt+3)*4096);
      qa1 = *(const bf16x8*)(wdB1 + (kt+3)*4096);
      acc[0][0]=MFMA16(c0,b0,acc[0][0]); acc[0][1]=MFMA16(c0,b1,acc[0][1]);
      acc[1][0]=MFMA16(c1,b0,acc[1][0]); acc[1][1]=MFMA16(c1,b1,acc[1][1]);
    }
    __syncthreads();                       // Vb dead -> Bc
    if (t<128) Bc[t*3] = 0;                // only unwritten im2col slot: x=0,tap0 (o=t)
    // ---- epilogue 1: bn+gelu+max_k, scatter S[o][p] -> im2col Bc[x][o*3+tap] ----
    #pragma unroll
    for (int r=0;r<2;r++){
      #pragma unroll
      for (int pt=0;pt<2;pt++){
        int ob = (wv+r*4)*16 + quad*4;
        int p  = pt*16 + col;
        float vv[4];
        #pragma unroll
        for (int reg=0;reg<4;reg++){
          float val = gelu_f(fmaf(acc[r][pt][reg], Pd[ob+reg], Pd[128+ob+reg]));
          if (pt==0) val = fmaxf(val, Pd[512+ob+reg]);   // p<16: max over k
          vv[reg] = val;
        }
        u32 pkA = cvtpk(vv[0], vv[1]);
        u32 pkB = cvtpk(vv[2], vv[3]);
        u16 bs0=(u16)pkA, bs1=(u16)(pkA>>16), bs2=(u16)pkB, bs3=(u16)(pkB>>16);
        if (p&1){
          u16* q = &Bc[((p-1)>>1)*392 + ob*3 + 2];
          q[0]=bs0; q[3]=bs1; q[6]=bs2; q[9]=bs3;
          if (p<31){
            u16* q2 = &Bc[((p+1)>>1)*392 + ob*3];
            q2[0]=bs0; q2[3]=bs1; q2[6]=bs2; q2[9]=bs3;
          }
        } else {
          u16* q = &Bc[(p>>1)*392 + ob*3 + 1];
          q[0]=bs0; q[3]=bs1; q[6]=bs2; q[9]=bs3;
        }
      }
    }
    // conv weight slots kt=0,1 prefetched above the barrier
    const u16* wcB0 = wcb + ((wv  )*64+lane)*8;       // kt stride = 4096 u16
    const u16* wcB1 = wcb + ((wv+4)*64+lane)*8;
    bf16x8 ca0 = *(const bf16x8*)(wcB0);
    bf16x8 ca1 = *(const bf16x8*)(wcB1);
    bf16x8 da0 = *(const bf16x8*)(wcB0 + 4096);
    bf16x8 da1 = *(const bf16x8*)(wcB1 + 4096);
    __syncthreads();
    // ---- conv: C[128o x 16x] = Wc[128o x 384k] * Bc[384k x 16x]; 2-deep pipe ----
    f32x4 cacc[2]={};
    #pragma unroll 1
    for (int kt=0;kt<12;kt+=2){
      bf16x8 cb0 = *(const bf16x8*)&Bc[col*392 + kt*32 + quad*8];
      bf16x8 c0=ca0, c1=ca1;
      ca0 = *(const bf16x8*)(wcB0 + (kt+2)*4096);     // tail reads into wsb: valid, dead regs
      ca1 = *(const bf16x8*)(wcB1 + (kt+2)*4096);
      cacc[0]=MFMA16(c0,cb0,cacc[0]);
      cacc[1]=MFMA16(c1,cb0,cacc[1]);
      cb0 = *(const bf16x8*)&Bc[col*392 + (kt+1)*32 + quad*8];
      c0=da0; c1=da1;
      da0 = *(const bf16x8*)(wcB0 + (kt+3)*4096);
      da1 = *(const bf16x8*)(wcB1 + (kt+3)*4096);
      cacc[0]=MFMA16(c0,cb0,cacc[0]);
      cacc[1]=MFMA16(c1,cb0,cacc[1]);
    }
    #pragma unroll
    for (int r=0;r<2;r++){
      #pragma unroll
      for (int reg=0;reg<4;reg++){
        int o = (wv+r*4)*16 + quad*4 + reg;
        float val = gelu_f(fmaf(cacc[r][reg], Pd[256+o], Pd[384+o]));
        out_dn[(b*128+o)*256 + m*16 + col] = val;
      }
    }
  }
}

extern "C" void kernel_launch(void* const* d_in, const int* in_sizes, int n_in,
                              void* d_out, int out_size, void* d_ws, size_t ws_size,
                              hipStream_t stream) {
  const float* sparse_fea = (const float*)d_in[0];
  const float* dense_fea  = (const float*)d_in[1];
  const float* stk_coor   = (const float*)d_in[2];
  // d_in[3] = n_stk_center (16, hardcoded)
  const float* sp_w  = (const float*)d_in[4];
  const float* sp_b  = (const float*)d_in[5];
  const float* sp_g  = (const float*)d_in[6];
  const float* sp_be = (const float*)d_in[7];
  const float* dn_w  = (const float*)d_in[8];
  const float* dn_b  = (const float*)d_in[9];
  const float* dn_g  = (const float*)d_in[10];
  const float* dn_be = (const float*)d_in[11];
  const float* ds_w  = (const float*)d_in[12];
  const float* ds_b  = (const float*)d_in[13];
  const float* ds_g  = (const float*)d_in[14];
  const float* ds_be = (const float*)d_in[15];

  float* out = (float*)d_out;
  // outputs: sparse [0, 524288) | dense [524288, 4718592) | coor [4718592, 4784128)
  int* fps_idx = (int*)d_ws;                              // [0, 16384) B
  int* nn_idx  = fps_idx + 2048;
  u16* wdb = (u16*)((char*)d_ws + 16384);                 // 64 KB  (8kt x 8ot)
  u16* wcb = (u16*)((char*)d_ws + 81920);                 // 96 KB  (12kt x 8ot)
  u16* wsb = (u16*)((char*)d_ws + 180224);                // 256 KB (16kt x 16ot)
  // NOTE: MFMA-loop tail prefetches intentionally read a few KB past each
  // weight region into the next one (valid ws memory, dead registers).

  k_prep<<<960, 256, 0, stream>>>(dn_w, ds_w, sp_w, stk_coor,
                                  wdb, wcb, wsb, fps_idx, nn_idx, out + 4718592);
  k_main<<<2176, 256, 0, stream>>>(sparse_fea, wsb, sp_b, sp_g, sp_be,
                                   dense_fea, wdb, dn_b, dn_g, dn_be,
                                   wcb, ds_b, ds_g, ds_be,
                                   fps_idx, nn_idx, out, out + 524288);
}